// Round 8
// baseline (229.280 us; speedup 1.0000x reference)
//
#include <hip/hip_runtime.h>
#include <hip/hip_cooperative_groups.h>

namespace cg = cooperative_groups;

// rosa_4bit_layer: causal linear attention, per-head 4x4 state.
//   S_t = S_{t-1} + k_t v_t^T ;  o_t = q_t^T S_t ;  out = o * emb
//
// R7 post-mortem: cooperative 512-block launch produced zeros => the launch
// itself failed (absmax == max|ref|; no deadlock). Prime suspect:
// hipErrorCooperativeLaunchTooLarge (512 blocks needs exactly 2 blocks/CU).
// R8: 256 blocks x 512 threads (co-resident at ANY vgpr<=256; each block owns
// 2 chunks), plus an error-checked fallback to the proven 3-kernel path.

constexpr int B   = 4;
constexpr int T   = 4096;
constexpr int C   = 512;
constexpr int CT  = 32;       // timesteps per chunk
constexpr int NC  = T / CT;   // 128 chunks
constexpr int SC  = 16;       // chunks per super-chunk
constexpr int NSC = NC / SC;  // 8 super-chunks
constexpr int CPB = 2;        // chunks per block (fused kernel)
// d_ws: part  B*NC*2048 floats (4 MiB), spart B*NSC*2048 floats (256 KiB)
constexpr size_t SPART_OFF = (size_t)B * NC * 2048;

// ---------------- shared per-chunk helpers (inlined) ----------------

__device__ __forceinline__ void chunk_partial(const float* __restrict__ k,
                                              const float* __restrict__ v,
                                              float* __restrict__ part,
                                              int bc, int tid) {
  const int b = bc / NC, c = bc % NC;
  const int h = tid >> 2, e = tid & 3;
  const size_t base = ((size_t)b * T + (size_t)c * CT) * (size_t)C + (h << 2);
  const float* kb = k + base;
  const float* vb = v + base + e;
  float4 acc = {0.f, 0.f, 0.f, 0.f};
#pragma unroll 8
  for (int t = 0; t < CT; ++t) {
    const float4 k4 = *reinterpret_cast<const float4*>(kb + (size_t)t * C);
    const float  ve = vb[(size_t)t * C];
    acc.x += k4.x * ve; acc.y += k4.y * ve;
    acc.z += k4.z * ve; acc.w += k4.w * ve;
  }
  reinterpret_cast<float4*>(part)[(size_t)bc * 512 + tid] = acc;
}

__device__ __forceinline__ void chunk_scan_out(const float* __restrict__ q,
                                               const float* __restrict__ k,
                                               const float* __restrict__ v,
                                               const float* __restrict__ emb,
                                               const float* __restrict__ part,
                                               const float* __restrict__ spart,
                                               float* __restrict__ out,
                                               int bc, int tid) {
  const int b = bc / NC, c = bc % NC;
  const int h = tid >> 2, e = tid & 3;
  const int s = c >> 4, cr = c & (SC - 1);

  float4 S = {0.f, 0.f, 0.f, 0.f};
  const float4* sp = reinterpret_cast<const float4*>(spart) + (size_t)b * NSC * 512 + tid;
#pragma unroll 4
  for (int i = 0; i < s; ++i) {
    const float4 x = sp[(size_t)i * 512];
    S.x += x.x; S.y += x.y; S.z += x.z; S.w += x.w;
  }
  const float4* pb = reinterpret_cast<const float4*>(part) +
                     ((size_t)(b * NC + s * SC)) * 512 + tid;
#pragma unroll 4
  for (int i = 0; i < cr; ++i) {
    const float4 x = pb[(size_t)i * 512];
    S.x += x.x; S.y += x.y; S.z += x.z; S.w += x.w;
  }

  const size_t base = ((size_t)b * T + (size_t)c * CT) * (size_t)C + (h << 2);
  const float* qb = q + base;
  const float* kb = k + base;
  const float* vb = v + base + e;
  float*       ob = out + base + e;
  const float embv = emb[(h << 2) + e];

#pragma unroll 8
  for (int t = 0; t < CT; ++t) {
    const float4 k4 = *reinterpret_cast<const float4*>(kb + (size_t)t * C);
    const float4 q4 = *reinterpret_cast<const float4*>(qb + (size_t)t * C);
    const float  ve = vb[(size_t)t * C];
    S.x += k4.x * ve; S.y += k4.y * ve;
    S.z += k4.z * ve; S.w += k4.w * ve;
    const float o = q4.x * S.x + q4.y * S.y + q4.z * S.z + q4.w * S.w;
    ob[(size_t)t * C] = o * embv;
  }
}

__device__ __forceinline__ void super_sum(const float* __restrict__ part,
                                          float* __restrict__ spart,
                                          int bs, int tid) {
  const int sb = bs / NSC, ss = bs % NSC;
  const float4* p4 = reinterpret_cast<const float4*>(part) +
                     ((size_t)(sb * NC + ss * SC)) * 512 + tid;
  float4 sa = {0.f, 0.f, 0.f, 0.f};
#pragma unroll
  for (int i = 0; i < SC; ++i) {
    const float4 x = p4[(size_t)i * 512];
    sa.x += x.x; sa.y += x.y; sa.z += x.z; sa.w += x.w;
  }
  reinterpret_cast<float4*>(spart)[(size_t)bs * 512 + tid] = sa;
}

// ---------------- fused cooperative kernel: 256 blocks x 512 ----------------

__global__ __launch_bounds__(512, 4) void rosa_fused(const float* __restrict__ q,
                                                     const float* __restrict__ k,
                                                     const float* __restrict__ v,
                                                     const float* __restrict__ emb,
                                                     float* __restrict__ part,
                                                     float* __restrict__ spart,
                                                     float* __restrict__ out) {
  const int tid = threadIdx.x;
#pragma unroll
  for (int i = 0; i < CPB; ++i)
    chunk_partial(k, v, part, blockIdx.x * CPB + i, tid);

  cg::this_grid().sync();

  if (blockIdx.x < B * NSC)
    super_sum(part, spart, blockIdx.x, tid);

  cg::this_grid().sync();

#pragma unroll
  for (int i = 0; i < CPB; ++i)
    chunk_scan_out(q, k, v, emb, part, spart, out, blockIdx.x * CPB + i, tid);
}

// ---------------- fallback 3-kernel path (proven, R6 = 151 us) ----------------

__global__ __launch_bounds__(512) void rosa_partial(const float* __restrict__ k,
                                                    const float* __restrict__ v,
                                                    float* __restrict__ part) {
  chunk_partial(k, v, part, blockIdx.x, threadIdx.x);
}

__global__ __launch_bounds__(512) void rosa_super(const float* __restrict__ part,
                                                  float* __restrict__ spart) {
  super_sum(part, spart, blockIdx.x, threadIdx.x);
}

__global__ __launch_bounds__(512) void rosa_scan_out(const float* __restrict__ q,
                                                     const float* __restrict__ k,
                                                     const float* __restrict__ v,
                                                     const float* __restrict__ emb,
                                                     const float* __restrict__ part,
                                                     const float* __restrict__ spart,
                                                     float* __restrict__ out) {
  chunk_scan_out(q, k, v, emb, part, spart, out, blockIdx.x, threadIdx.x);
}

extern "C" void kernel_launch(void* const* d_in, const int* in_sizes, int n_in,
                              void* d_out, int out_size, void* d_ws, size_t ws_size,
                              hipStream_t stream) {
  const float* xq  = (const float*)d_in[0];
  const float* xk  = (const float*)d_in[1];
  const float* xv  = (const float*)d_in[2];
  const float* emb = (const float*)d_in[3];
  float* out   = (float*)d_out;
  float* part  = (float*)d_ws;
  float* spart = part + SPART_OFF;

  void* args[] = {(void*)&xq, (void*)&xk, (void*)&xv, (void*)&emb,
                  (void*)&part, (void*)&spart, (void*)&out};
  hipError_t err = hipLaunchCooperativeKernel((const void*)rosa_fused,
                                              dim3(B * NC / CPB), dim3(512),
                                              args, 0, stream);
  if (err != hipSuccess) {
    // Deterministic fallback (same environment -> same path every call).
    rosa_partial<<<B * NC, 512, 0, stream>>>(xk, xv, part);
    rosa_super<<<B * NSC, 512, 0, stream>>>(part, spart);
    rosa_scan_out<<<B * NC, 512, 0, stream>>>(xq, xk, xv, emb, part, spart, out);
  }
}

// Round 9
// 162.898 us; speedup vs baseline: 1.4075x; 1.4075x over previous
//
#include <hip/hip_runtime.h>

// rosa_4bit_layer: causal linear attention, per-head 4x4 state.
//   S_t = S_{t-1} + k_t v_t^T ;  o_t = q_t^T S_t ;  out = o * emb
// x{q,k,v}: (B=4, T=4096, C=512) fp32; emb broadcast (512).
//
// R8 post-mortem: fused cooperative kernel (256 blocks = 1 block/CU) ran at
// 110us, 16% HBM, VALU 3% -- wave-level MLP is the limiter (Little's law:
// 8 waves/CU x ~24 loads x 256B / 900cyc ~= 3.4 B/cyc/CU vs 10 needed).
// Fusion halved occupancy and added 2 grid syncs; reverted.
// R9: 3-kernel path with CT=16 -> 1024 blocks x 512 thr = 4 blocks/CU =
// 32 waves/CU (hardware max) for partial & scan_out. launch_bounds(512,8)
// caps VGPR at 64 to guarantee 8 waves/SIMD.

constexpr int B   = 4;
constexpr int T   = 4096;
constexpr int C   = 512;
constexpr int CT  = 16;       // timesteps per chunk
constexpr int NC  = T / CT;   // 256 chunks per sequence
constexpr int SC  = 16;       // chunks per super-chunk
constexpr int NSC = NC / SC;  // 16 super-chunks
// d_ws: part  B*NC*2048 floats (8 MiB), spart B*NSC*2048 floats (512 KiB)
constexpr size_t SPART_OFF = (size_t)B * NC * 2048;

__global__ __launch_bounds__(512, 8) void rosa_partial(const float* __restrict__ k,
                                                       const float* __restrict__ v,
                                                       float* __restrict__ part) {
  const int bc  = blockIdx.x;            // b*NC + c
  const int b   = bc / NC;
  const int c   = bc % NC;
  const int tid = threadIdx.x;           // 0..511
  const int h   = tid >> 2;
  const int e   = tid & 3;

  const size_t base = ((size_t)b * T + (size_t)c * CT) * (size_t)C + (h << 2);
  const float* kb = k + base;
  const float* vb = v + base + e;

  float4 acc = {0.f, 0.f, 0.f, 0.f};
#pragma unroll 8
  for (int t = 0; t < CT; ++t) {
    const float4 k4 = *reinterpret_cast<const float4*>(kb + (size_t)t * C);
    const float  ve = vb[(size_t)t * C];
    acc.x += k4.x * ve;
    acc.y += k4.y * ve;
    acc.z += k4.z * ve;
    acc.w += k4.w * ve;
  }
  reinterpret_cast<float4*>(part)[(size_t)bc * 512 + tid] = acc;
}

// Sum SC consecutive chunk partials -> one super partial. grid: B*NSC = 64.
__global__ __launch_bounds__(512, 8) void rosa_super(const float* __restrict__ part,
                                                     float* __restrict__ spart) {
  const int bs  = blockIdx.x;            // b*NSC + s
  const int b   = bs / NSC;
  const int s   = bs % NSC;
  const int tid = threadIdx.x;

  const float4* p4 = reinterpret_cast<const float4*>(part) +
                     ((size_t)(b * NC + s * SC)) * 512 + tid;
  float4 acc = {0.f, 0.f, 0.f, 0.f};
#pragma unroll
  for (int i = 0; i < SC; ++i) {
    const float4 x = p4[(size_t)i * 512];
    acc.x += x.x; acc.y += x.y; acc.z += x.z; acc.w += x.w;
  }
  reinterpret_cast<float4*>(spart)[(size_t)bs * 512 + tid] = acc;
}

__global__ __launch_bounds__(512, 8) void rosa_scan_out(const float* __restrict__ q,
                                                        const float* __restrict__ k,
                                                        const float* __restrict__ v,
                                                        const float* __restrict__ emb,
                                                        const float* __restrict__ part,
                                                        const float* __restrict__ spart,
                                                        float* __restrict__ out) {
  const int bc  = blockIdx.x;
  const int b   = bc / NC;
  const int c   = bc % NC;
  const int tid = threadIdx.x;
  const int h   = tid >> 2;
  const int e   = tid & 3;
  const int s   = c >> 4;                // c / SC   (0..15)
  const int cr  = c & (SC - 1);          // c % SC   (0..15)

  // --- exclusive prefix: supers 0..s-1, then chunks s*SC .. c-1.
  float4 S = {0.f, 0.f, 0.f, 0.f};
  const float4* sp = reinterpret_cast<const float4*>(spart) + (size_t)b * NSC * 512 + tid;
#pragma unroll 4
  for (int i = 0; i < s; ++i) {
    const float4 x = sp[(size_t)i * 512];
    S.x += x.x; S.y += x.y; S.z += x.z; S.w += x.w;
  }
  const float4* pb = reinterpret_cast<const float4*>(part) +
                     ((size_t)(b * NC + s * SC)) * 512 + tid;
#pragma unroll 4
  for (int i = 0; i < cr; ++i) {
    const float4 x = pb[(size_t)i * 512];
    S.x += x.x; S.y += x.y; S.z += x.z; S.w += x.w;
  }

  // --- replay this chunk from its start state and write output.
  const size_t base = ((size_t)b * T + (size_t)c * CT) * (size_t)C + (h << 2);
  const float* qb = q + base;
  const float* kb = k + base;
  const float* vb = v + base + e;
  float*       ob = out + base + e;
  const float embv = emb[(h << 2) + e];

#pragma unroll 8
  for (int t = 0; t < CT; ++t) {
    const float4 k4 = *reinterpret_cast<const float4*>(kb + (size_t)t * C);
    const float4 q4 = *reinterpret_cast<const float4*>(qb + (size_t)t * C);
    const float  ve = vb[(size_t)t * C];
    S.x += k4.x * ve;
    S.y += k4.y * ve;
    S.z += k4.z * ve;
    S.w += k4.w * ve;
    const float o = q4.x * S.x + q4.y * S.y + q4.z * S.z + q4.w * S.w;
    ob[(size_t)t * C] = o * embv;
  }
}

extern "C" void kernel_launch(void* const* d_in, const int* in_sizes, int n_in,
                              void* d_out, int out_size, void* d_ws, size_t ws_size,
                              hipStream_t stream) {
  const float* xq  = (const float*)d_in[0];
  const float* xk  = (const float*)d_in[1];
  const float* xv  = (const float*)d_in[2];
  const float* emb = (const float*)d_in[3];
  float* out   = (float*)d_out;
  float* part  = (float*)d_ws;
  float* spart = part + SPART_OFF;

  rosa_partial<<<B * NC, 512, 0, stream>>>(xk, xv, part);
  rosa_super<<<B * NSC, 512, 0, stream>>>(part, spart);
  rosa_scan_out<<<B * NC, 512, 0, stream>>>(xq, xk, xv, emb, part, spart, out);
}